// Round 10
// baseline (214.375 us; speedup 1.0000x reference)
//
#include <hip/hip_runtime.h>

typedef float  f32x4  __attribute__((ext_vector_type(4)));
typedef short  s16x8  __attribute__((ext_vector_type(8)));
typedef short  s16x4  __attribute__((ext_vector_type(4)));

#define NROWS (2048 * 128)
#define PASSES 4         // 16-row passes per wave; 4x16x4 = 256 rows/block
#define HS 104           // act LDS stride in shorts
#define EPSF 1e-8f

union Frag { s16x8 v; unsigned short u[8]; };

// fp32 -> bf16 RTNE (verified R3-R9, absmax 0.0)
__device__ __forceinline__ unsigned short f2bf(float f) {
    unsigned int u = __float_as_uint(f);
    u += 0x7fffu + ((u >> 16) & 1u);
    return (unsigned short)(u >> 16);
}

// ---------------------------------------------------------------------------
// Pre-kernel: repack weights to bf16 MFMA B-fragment order (logic unchanged).
// NEW ws layout (so W1+biases are one contiguous 25536 B LDS-stage chunk):
//   [acc 1024][w1f 24576][b1 384][b2 320][b3 256][w2f 15360][w3f 12288]
// ---------------------------------------------------------------------------
__global__ void repack(const float* __restrict__ W1, const float* __restrict__ b1,
                       const float* __restrict__ W2, const float* __restrict__ b2,
                       const float* __restrict__ W3, const float* __restrict__ b3,
                       unsigned short* __restrict__ w1f, unsigned short* __restrict__ w2f,
                       unsigned short* __restrict__ w3f,
                       float* __restrict__ b1p, float* __restrict__ b2p,
                       float* __restrict__ b3p)
{
    const int b = blockIdx.x;
    const int l = threadIdx.x;      // 64 threads
    const int g = l >> 4, sl = l & 15;

    if (b < 24) {                   // W1: nt = b>>2, ks = b&3
        const int nt = b >> 2, ks = b & 3;
        const int o = nt * 16 + sl, kb = ks * 32 + g * 8;
        s16x8 v;
#pragma unroll
        for (int j = 0; j < 8; ++j) v[j] = (short)f2bf(W1[o * 128 + kb + j]);
        *(s16x8*)&w1f[b * 512 + l * 8] = v;
    } else if (b < 39) {            // W2 (out padded 72->80)
        const int f = b - 24, nt = f / 3, ks = f % 3;
        const int o = nt * 16 + sl, kb = ks * 32 + g * 8;
        s16x8 v;
#pragma unroll
        for (int j = 0; j < 8; ++j)
            v[j] = (short)((o < 72) ? f2bf(W2[o * 96 + kb + j]) : 0);
        *(s16x8*)&w2f[f * 512 + l * 8] = v;
    } else if (b < 51) {            // W3 (k padded 72->96)
        const int f = b - 39, nt = f / 3, ks = f % 3;
        const int o = nt * 16 + sl, kb = ks * 32 + g * 8;
        s16x8 v;
#pragma unroll
        for (int j = 0; j < 8; ++j)
            v[j] = (short)((kb + j < 72) ? f2bf(W3[o * 72 + kb + j]) : 0);
        *(s16x8*)&w3f[f * 512 + l * 8] = v;
    } else {                        // biases, zero-padded
        for (int i = l; i < 240; i += 64) {
            if (i < 96)       b1p[i] = b1[i];
            else if (i < 176) { int o = i - 96; b2p[o] = (o < 72) ? b2[o] : 0.f; }
            else              b3p[i - 176] = b3[i - 176];
        }
    }
}

// ---------------------------------------------------------------------------
// Main. OCCUPANCY-FIRST redesign: LDS holds only W1+biases (25.5 KB) + act
// (13.3 KB) = 39.9 KB -> 4 blocks/CU = 16 waves/CU (2x R5's TLP). W2/W3
// frags are read from GLOBAL (27 KB, hot in L2 across all CUs, ~200cyc --
// covered by TLP). No register prefetch: latency hiding now comes from
// waves, not hoisted loads, so per-pass live state (~85 VGPR) fits the
// 128-VGPR budget without the R5-R9 scratch spills.
// grid = 1024 blocks = exactly 4 resident/CU, one round.
// ---------------------------------------------------------------------------
__global__ __launch_bounds__(256, 4)
void mlp_main(const float* __restrict__ x,
              const f32x4* __restrict__ w1src,          // W1 frags + biases (1596 x 16 B)
              const unsigned short* __restrict__ w2f,   // 15 frags, global (L2-hot)
              const unsigned short* __restrict__ w3f,   // 12 frags, global (L2-hot)
              float* __restrict__ acc /* [65]: s[64], uu */)
{
    __shared__ __align__(16) unsigned char  wb[25536];        // W1 frags | b1 | b2 | b3
    __shared__ __align__(16) unsigned short act[4][16][HS];   // 13.3 KB wave-private
    __shared__ float sred[4][64];
    __shared__ float uured[4];

    const unsigned short* w1L = (const unsigned short*)wb;    // 24 frags
    const float* b1L = (const float*)(wb + 24576);            // 96
    const float* b2L = b1L + 96;                              // 80
    const float* b3L = b1L + 176;                             // 64

    const int tid  = threadIdx.x;
    const int lane = tid & 63;
    const int wv   = tid >> 6;
    const int g    = lane >> 4;
    const int sl   = lane & 15;

    // ---- stage W1 + biases to LDS (25536 B = 1596 f32x4) ----
    for (int i = tid; i < 1596; i += 256)
        ((f32x4*)wb)[i] = w1src[i];
    __syncthreads();

    // lane-fixed x base: row sl, cols g*8 .. (+ks*32)
    const float* xwave = x + ((size_t)(blockIdx.x * 4 + wv) * (16 * PASSES)) * 128
                         + sl * 128 + g * 8;

    float uu_part = 0.f;
    float s_part[4] = {0.f, 0.f, 0.f, 0.f};

#pragma unroll 1        // rolled: one pass live at a time; TLP hides latency
    for (int p = 0; p < PASSES; ++p) {
        // ---- load this pass's x (8 x dwordx4, one vmcnt wait) ----
        const float* xw = xwave + (size_t)p * (16 * 128);
        f32x4 t[8];
#pragma unroll
        for (int ks = 0; ks < 4; ++ks) {
            t[ks * 2 + 0] = *(const f32x4*)(xw + ks * 32);
            t[ks * 2 + 1] = *(const f32x4*)(xw + ks * 32 + 4);
        }
        Frag A1[4];
#pragma unroll
        for (int ks = 0; ks < 4; ++ks)
#pragma unroll
            for (int j = 0; j < 4; ++j) {
                A1[ks].u[j]     = f2bf(t[ks * 2 + 0][j]);
                A1[ks].u[4 + j] = f2bf(t[ks * 2 + 1][j]);
            }

        // ================= layer 1: 128 -> 96 (W1 from LDS) =================
        f32x4 D1[6];
#pragma unroll
        for (int nt = 0; nt < 6; ++nt) {
            const float bb = b1L[nt * 16 + sl];
            D1[nt] = (f32x4){bb, bb, bb, bb};
        }
#pragma unroll
        for (int ks = 0; ks < 4; ++ks)
#pragma unroll
            for (int nt = 0; nt < 6; ++nt) {
                const s16x8 B = *(const s16x8*)&w1L[(nt * 4 + ks) * 512 + lane * 8];
                D1[nt] = __builtin_amdgcn_mfma_f32_16x16x32_bf16(A1[ks].v, B, D1[nt], 0, 0, 0);
            }
        // relu + write h1[sample = g*4+r][feat = nt*16+sl] (wave-private)
#pragma unroll
        for (int nt = 0; nt < 6; ++nt)
#pragma unroll
            for (int r = 0; r < 4; ++r)
                act[wv][g * 4 + r][nt * 16 + sl] = f2bf(fmaxf(D1[nt][r], 0.f));

        // layer-2 A-frags: feats 0..95 of sample sl
        Frag A2[3];
#pragma unroll
        for (int ks = 0; ks < 3; ++ks)
            A2[ks].v = *(const s16x8*)&act[wv][sl][ks * 32 + g * 8];

        // zero pad feats 80..95 for the h2 tile (read by L3 ks=2)
        {
            const s16x4 z = (s16x4){0, 0, 0, 0};
            *(s16x4*)&act[wv][sl][80 + g * 4] = z;
        }

        // ============== layer 2: 96 -> 72 (pad 80; W2 from GLOBAL) ==============
        f32x4 D2[5];
#pragma unroll
        for (int nt = 0; nt < 5; ++nt) {
            const float bb = b2L[nt * 16 + sl];
            D2[nt] = (f32x4){bb, bb, bb, bb};
        }
#pragma unroll
        for (int ks = 0; ks < 3; ++ks)
#pragma unroll
            for (int nt = 0; nt < 5; ++nt) {
                const s16x8 B = *(const s16x8*)&w2f[(nt * 3 + ks) * 512 + lane * 8];
                D2[nt] = __builtin_amdgcn_mfma_f32_16x16x32_bf16(A2[ks].v, B, D2[nt], 0, 0, 0);
            }
#pragma unroll
        for (int nt = 0; nt < 5; ++nt)
#pragma unroll
            for (int r = 0; r < 4; ++r)
                act[wv][g * 4 + r][nt * 16 + sl] = f2bf(fmaxf(D2[nt][r], 0.f));

        // layer-3 A-frags: h2 feats 0..95 (72..95 structurally zero)
        Frag A3[3];
#pragma unroll
        for (int ks = 0; ks < 3; ++ks)
            A3[ks].v = *(const s16x8*)&act[wv][sl][ks * 32 + g * 8];

        // ============== layer 3: 72 (pad 96) -> 64 (W3 from GLOBAL) ==============
        f32x4 D3[4];
#pragma unroll
        for (int nt = 0; nt < 4; ++nt) {
            const float bb = b3L[nt * 16 + sl];
            D3[nt] = (f32x4){bb, bb, bb, bb};
        }
#pragma unroll
        for (int ks = 0; ks < 3; ++ks)
#pragma unroll
            for (int nt = 0; nt < 4; ++nt) {
                const s16x8 B = *(const s16x8*)&w3f[(nt * 3 + ks) * 512 + lane * 8];
                D3[nt] = __builtin_amdgcn_mfma_f32_16x16x32_bf16(A3[ks].v, B, D3[nt], 0, 0, 0);
            }

        // ===== epilogue: row norm; accumulate s/uu across passes =====
        float ffr[4];
#pragma unroll
        for (int r = 0; r < 4; ++r) {
            float a = 0.f;
#pragma unroll
            for (int nt = 0; nt < 4; ++nt)
                a = fmaf(D3[nt][r], D3[nt][r], a);
            ffr[r] = a;
        }
#pragma unroll
        for (int r = 0; r < 4; ++r) {
            ffr[r] += __shfl_xor(ffr[r], 1, 64);
            ffr[r] += __shfl_xor(ffr[r], 2, 64);
            ffr[r] += __shfl_xor(ffr[r], 4, 64);
            ffr[r] += __shfl_xor(ffr[r], 8, 64);
        }
        float inv[4];
#pragma unroll
        for (int r = 0; r < 4; ++r) {
            inv[r] = 1.f / fmaxf(sqrtf(ffr[r]), EPSF);
            uu_part = fmaf(ffr[r] * inv[r], inv[r], uu_part);  // dup x16 over sl
        }
#pragma unroll
        for (int nt = 0; nt < 4; ++nt)
#pragma unroll
            for (int r = 0; r < 4; ++r)
                s_part[nt] = fmaf(D3[nt][r], inv[r], s_part[nt]);
    }

    // cross-g reduction (once, after all passes)
#pragma unroll
    for (int nt = 0; nt < 4; ++nt) {
        s_part[nt] += __shfl_xor(s_part[nt], 16, 64);
        s_part[nt] += __shfl_xor(s_part[nt], 32, 64);
    }
    uu_part += __shfl_xor(uu_part, 16, 64);
    uu_part += __shfl_xor(uu_part, 32, 64);

    if (g == 0) {
#pragma unroll
        for (int nt = 0; nt < 4; ++nt) sred[wv][nt * 16 + sl] = s_part[nt];
    }
    if (lane == 0) uured[wv] = uu_part * 0.0625f;
    __syncthreads();

    if (tid < 64) {
        const float t = sred[0][tid] + sred[1][tid] + sred[2][tid] + sred[3][tid];
        atomicAdd(&acc[tid], t);
    }
    if (tid == 0)
        atomicAdd(&acc[64], uured[0] + uured[1] + uured[2] + uured[3]);
}

__global__ void finalize_k(const float* __restrict__ acc, float* __restrict__ out)
{
    float s = acc[threadIdx.x];
    float d = s * s;
#pragma unroll
    for (int off = 32; off > 0; off >>= 1)
        d += __shfl_xor(d, off, 64);
    if (threadIdx.x == 0)
        out[0] = 0.5f * (d - acc[64]) / (float)NROWS;
}

extern "C" void kernel_launch(void* const* d_in, const int* in_sizes, int n_in,
                              void* d_out, int out_size, void* d_ws, size_t ws_size,
                              hipStream_t stream)
{
    const float* x  = (const float*)d_in[0];
    const float* W1 = (const float*)d_in[1];
    const float* b1 = (const float*)d_in[2];
    const float* W2 = (const float*)d_in[3];
    const float* b2 = (const float*)d_in[4];
    const float* W3 = (const float*)d_in[5];
    const float* b3 = (const float*)d_in[6];

    char* ws = (char*)d_ws;
    // layout: [acc 1024][w1f 24576][b1 384][b2 320][b3 256][w2f 15360][w3f 12288]
    float*          acc = (float*)ws;
    unsigned short* w1f = (unsigned short*)(ws + 1024);
    float*          b1p = (float*)(ws + 25600);
    float*          b2p = (float*)(ws + 25984);
    float*          b3p = (float*)(ws + 26304);
    unsigned short* w2f = (unsigned short*)(ws + 26560);
    unsigned short* w3f = (unsigned short*)(ws + 41920);

    hipMemsetAsync(acc, 0, 1024, stream);
    repack<<<52, 64, 0, stream>>>(W1, b1, W2, b2, W3, b3, w1f, w2f, w3f, b1p, b2p, b3p);
    // 1024 blocks x 4 waves x 4 passes x 16 rows = 262144 rows
    mlp_main<<<NROWS / (4 * PASSES * 16), 256, 0, stream>>>(
        x, (const f32x4*)(ws + 1024), w2f, w3f, acc);
    finalize_k<<<1, 64, 0, stream>>>(acc, (float*)d_out);
}

// Round 11
// 71.557 us; speedup vs baseline: 2.9959x; 2.9959x over previous
//
#include <hip/hip_runtime.h>

typedef float  f32x4  __attribute__((ext_vector_type(4)));
typedef short  s16x8  __attribute__((ext_vector_type(8)));
typedef short  s16x4  __attribute__((ext_vector_type(4)));

#define NROWS (2048 * 128)
#define PASSES 4         // 16-row passes per wave; 4 waves x 4 x 16 = 256 rows/block
#define HS 104           // act LDS stride in shorts
#define EPSF 1e-8f

union Frag { s16x8 v; unsigned short u[8]; };

// fp32 -> bf16 RTNE (verified R3-R10, absmax 0.0)
__device__ __forceinline__ unsigned short f2bf(float f) {
    unsigned int u = __float_as_uint(f);
    u += 0x7fffu + ((u >> 16) & 1u);
    return (unsigned short)(u >> 16);
}

// ---------------------------------------------------------------------------
// Pre-kernel: repack weights to bf16 MFMA B-fragment order (unchanged).
// ws layout: [acc 1024][w1f 24576][b1 384][b2 320][b3 256][w2f 15360][w3f 12288]
// ---------------------------------------------------------------------------
__global__ void repack(const float* __restrict__ W1, const float* __restrict__ b1,
                       const float* __restrict__ W2, const float* __restrict__ b2,
                       const float* __restrict__ W3, const float* __restrict__ b3,
                       unsigned short* __restrict__ w1f, unsigned short* __restrict__ w2f,
                       unsigned short* __restrict__ w3f,
                       float* __restrict__ b1p, float* __restrict__ b2p,
                       float* __restrict__ b3p)
{
    const int b = blockIdx.x;
    const int l = threadIdx.x;      // 64 threads
    const int g = l >> 4, sl = l & 15;

    if (b < 24) {                   // W1: nt = b>>2, ks = b&3
        const int nt = b >> 2, ks = b & 3;
        const int o = nt * 16 + sl, kb = ks * 32 + g * 8;
        s16x8 v;
#pragma unroll
        for (int j = 0; j < 8; ++j) v[j] = (short)f2bf(W1[o * 128 + kb + j]);
        *(s16x8*)&w1f[b * 512 + l * 8] = v;
    } else if (b < 39) {            // W2 (out padded 72->80)
        const int f = b - 24, nt = f / 3, ks = f % 3;
        const int o = nt * 16 + sl, kb = ks * 32 + g * 8;
        s16x8 v;
#pragma unroll
        for (int j = 0; j < 8; ++j)
            v[j] = (short)((o < 72) ? f2bf(W2[o * 96 + kb + j]) : 0);
        *(s16x8*)&w2f[f * 512 + l * 8] = v;
    } else if (b < 51) {            // W3 (k padded 72->96)
        const int f = b - 39, nt = f / 3, ks = f % 3;
        const int o = nt * 16 + sl, kb = ks * 32 + g * 8;
        s16x8 v;
#pragma unroll
        for (int j = 0; j < 8; ++j)
            v[j] = (short)((kb + j < 72) ? f2bf(W3[o * 72 + kb + j]) : 0);
        *(s16x8*)&w3f[f * 512 + l * 8] = v;
    } else {                        // biases, zero-padded
        for (int i = l; i < 240; i += 64) {
            if (i < 96)       b1p[i] = b1[i];
            else if (i < 176) { int o = i - 96; b2p[o] = (o < 72) ? b2[o] : 0.f; }
            else              b3p[i - 176] = b3[i - 176];
        }
    }
}

// ---------------------------------------------------------------------------
// Main. R10's occupancy-friendly memory layout (W1+biases LDS = 25.5 KB,
// act 13.3 KB -> total 39.9 KB; W2/W3 from L2) + R5's pass-ahead x prefetch
// + __launch_bounds__(256, 1): 10 rounds of data show lb(256,1) is the ONLY
// setting where the allocator does not clamp VGPRs below live state and
// spill (R2: 140 VGPR, 288 B writes). lb(256,{2,3,4}) clamped to
// 128/84/64 VGPR and spilled 21/95/206 MB. With ~120 VGPR live (pass state
// + prefetch), expect ~140-170 allocated -> 3 waves/EU, zero scratch.
// #pragma unroll 1 bounds the scheduler's hoisting scope to one pass.
// ---------------------------------------------------------------------------
__global__ __launch_bounds__(256, 1)
void mlp_main(const float* __restrict__ x,
              const f32x4* __restrict__ w1src,          // W1 frags + biases (1596 x 16 B)
              const unsigned short* __restrict__ w2f,   // 15 frags, global (L2-hot)
              const unsigned short* __restrict__ w3f,   // 12 frags, global (L2-hot)
              float* __restrict__ acc /* [65]: s[64], uu */)
{
    __shared__ __align__(16) unsigned char  wb[25536];        // W1 frags | b1 | b2 | b3
    __shared__ __align__(16) unsigned short act[4][16][HS];   // 13.3 KB wave-private
    __shared__ float sred[4][64];
    __shared__ float uured[4];

    const unsigned short* w1L = (const unsigned short*)wb;    // 24 frags
    const float* b1L = (const float*)(wb + 24576);            // 96
    const float* b2L = b1L + 96;                              // 80
    const float* b3L = b1L + 176;                             // 64

    const int tid  = threadIdx.x;
    const int lane = tid & 63;
    const int wv   = tid >> 6;
    const int g    = lane >> 4;
    const int sl   = lane & 15;

    // lane-fixed x base: row sl, cols g*8 (+ks*32)
    const float* xwave = x + ((size_t)(blockIdx.x * 4 + wv) * (16 * PASSES)) * 128
                         + sl * 128 + g * 8;

    auto loadx = [&](f32x4 (&xp)[8], int p) {
        const float* xw = xwave + (size_t)p * (16 * 128);
#pragma unroll
        for (int ks = 0; ks < 4; ++ks) {
            xp[ks * 2 + 0] = *(const f32x4*)(xw + ks * 32);
            xp[ks * 2 + 1] = *(const f32x4*)(xw + ks * 32 + 4);
        }
    };

    // ---- issue pass-0 x loads BEFORE weight staging (overlap) ----
    f32x4 xp[8];
    loadx(xp, 0);

    // ---- stage W1 + biases to LDS (25536 B = 1596 f32x4) ----
    for (int i = tid; i < 1596; i += 256)
        ((f32x4*)wb)[i] = w1src[i];
    __syncthreads();

    float uu_part = 0.f;
    float s_part[4] = {0.f, 0.f, 0.f, 0.f};

#pragma unroll 1        // bound hoisting scope to one pass
    for (int p = 0; p < PASSES; ++p) {
        // convert this pass's x to A-frags (frees xp for the next prefetch)
        Frag A1[4];
#pragma unroll
        for (int ks = 0; ks < 4; ++ks)
#pragma unroll
            for (int j = 0; j < 4; ++j) {
                A1[ks].u[j]     = f2bf(xp[ks * 2 + 0][j]);
                A1[ks].u[4 + j] = f2bf(xp[ks * 2 + 1][j]);
            }

        // prefetch next pass (lands during L1+L2+L3 compute)
        if (p + 1 < PASSES) loadx(xp, p + 1);

        // ================= layer 1: 128 -> 96 (W1 from LDS) =================
        f32x4 D1[6];
#pragma unroll
        for (int nt = 0; nt < 6; ++nt) {
            const float bb = b1L[nt * 16 + sl];
            D1[nt] = (f32x4){bb, bb, bb, bb};
        }
#pragma unroll
        for (int ks = 0; ks < 4; ++ks)
#pragma unroll
            for (int nt = 0; nt < 6; ++nt) {
                const s16x8 B = *(const s16x8*)&w1L[(nt * 4 + ks) * 512 + lane * 8];
                D1[nt] = __builtin_amdgcn_mfma_f32_16x16x32_bf16(A1[ks].v, B, D1[nt], 0, 0, 0);
            }
        // relu + write h1[sample = g*4+r][feat = nt*16+sl] (wave-private)
#pragma unroll
        for (int nt = 0; nt < 6; ++nt)
#pragma unroll
            for (int r = 0; r < 4; ++r)
                act[wv][g * 4 + r][nt * 16 + sl] = f2bf(fmaxf(D1[nt][r], 0.f));

        // layer-2 A-frags: feats 0..95 of sample sl
        Frag A2[3];
#pragma unroll
        for (int ks = 0; ks < 3; ++ks)
            A2[ks].v = *(const s16x8*)&act[wv][sl][ks * 32 + g * 8];

        // zero pad feats 80..95 for the h2 tile (read by L3 ks=2)
        {
            const s16x4 z = (s16x4){0, 0, 0, 0};
            *(s16x4*)&act[wv][sl][80 + g * 4] = z;
        }

        // ============== layer 2: 96 -> 72 (pad 80; W2 from L2) ==============
        f32x4 D2[5];
#pragma unroll
        for (int nt = 0; nt < 5; ++nt) {
            const float bb = b2L[nt * 16 + sl];
            D2[nt] = (f32x4){bb, bb, bb, bb};
        }
#pragma unroll
        for (int ks = 0; ks < 3; ++ks)
#pragma unroll
            for (int nt = 0; nt < 5; ++nt) {
                const s16x8 B = *(const s16x8*)&w2f[(nt * 3 + ks) * 512 + lane * 8];
                D2[nt] = __builtin_amdgcn_mfma_f32_16x16x32_bf16(A2[ks].v, B, D2[nt], 0, 0, 0);
            }
#pragma unroll
        for (int nt = 0; nt < 5; ++nt)
#pragma unroll
            for (int r = 0; r < 4; ++r)
                act[wv][g * 4 + r][nt * 16 + sl] = f2bf(fmaxf(D2[nt][r], 0.f));

        // layer-3 A-frags: h2 feats 0..95 (72..95 structurally zero)
        Frag A3[3];
#pragma unroll
        for (int ks = 0; ks < 3; ++ks)
            A3[ks].v = *(const s16x8*)&act[wv][sl][ks * 32 + g * 8];

        // ============== layer 3: 72 (pad 96) -> 64 (W3 from L2) ==============
        f32x4 D3[4];
#pragma unroll
        for (int nt = 0; nt < 4; ++nt) {
            const float bb = b3L[nt * 16 + sl];
            D3[nt] = (f32x4){bb, bb, bb, bb};
        }
#pragma unroll
        for (int ks = 0; ks < 3; ++ks)
#pragma unroll
            for (int nt = 0; nt < 4; ++nt) {
                const s16x8 B = *(const s16x8*)&w3f[(nt * 3 + ks) * 512 + lane * 8];
                D3[nt] = __builtin_amdgcn_mfma_f32_16x16x32_bf16(A3[ks].v, B, D3[nt], 0, 0, 0);
            }

        // ===== epilogue: row norm; accumulate s/uu across passes =====
        float ffr[4];
#pragma unroll
        for (int r = 0; r < 4; ++r) {
            float a = 0.f;
#pragma unroll
            for (int nt = 0; nt < 4; ++nt)
                a = fmaf(D3[nt][r], D3[nt][r], a);
            ffr[r] = a;
        }
#pragma unroll
        for (int r = 0; r < 4; ++r) {
            ffr[r] += __shfl_xor(ffr[r], 1, 64);
            ffr[r] += __shfl_xor(ffr[r], 2, 64);
            ffr[r] += __shfl_xor(ffr[r], 4, 64);
            ffr[r] += __shfl_xor(ffr[r], 8, 64);
        }
        float inv[4];
#pragma unroll
        for (int r = 0; r < 4; ++r) {
            inv[r] = 1.f / fmaxf(sqrtf(ffr[r]), EPSF);
            uu_part = fmaf(ffr[r] * inv[r], inv[r], uu_part);  // dup x16 over sl
        }
#pragma unroll
        for (int nt = 0; nt < 4; ++nt)
#pragma unroll
            for (int r = 0; r < 4; ++r)
                s_part[nt] = fmaf(D3[nt][r], inv[r], s_part[nt]);
    }

    // cross-g reduction (once, after all passes)
#pragma unroll
    for (int nt = 0; nt < 4; ++nt) {
        s_part[nt] += __shfl_xor(s_part[nt], 16, 64);
        s_part[nt] += __shfl_xor(s_part[nt], 32, 64);
    }
    uu_part += __shfl_xor(uu_part, 16, 64);
    uu_part += __shfl_xor(uu_part, 32, 64);

    if (g == 0) {
#pragma unroll
        for (int nt = 0; nt < 4; ++nt) sred[wv][nt * 16 + sl] = s_part[nt];
    }
    if (lane == 0) uured[wv] = uu_part * 0.0625f;
    __syncthreads();

    if (tid < 64) {
        const float t = sred[0][tid] + sred[1][tid] + sred[2][tid] + sred[3][tid];
        atomicAdd(&acc[tid], t);
    }
    if (tid == 0)
        atomicAdd(&acc[64], uured[0] + uured[1] + uured[2] + uured[3]);
}

__global__ void finalize_k(const float* __restrict__ acc, float* __restrict__ out)
{
    float s = acc[threadIdx.x];
    float d = s * s;
#pragma unroll
    for (int off = 32; off > 0; off >>= 1)
        d += __shfl_xor(d, off, 64);
    if (threadIdx.x == 0)
        out[0] = 0.5f * (d - acc[64]) / (float)NROWS;
}

extern "C" void kernel_launch(void* const* d_in, const int* in_sizes, int n_in,
                              void* d_out, int out_size, void* d_ws, size_t ws_size,
                              hipStream_t stream)
{
    const float* x  = (const float*)d_in[0];
    const float* W1 = (const float*)d_in[1];
    const float* b1 = (const float*)d_in[2];
    const float* W2 = (const float*)d_in[3];
    const float* b2 = (const float*)d_in[4];
    const float* W3 = (const float*)d_in[5];
    const float* b3 = (const float*)d_in[6];

    char* ws = (char*)d_ws;
    // layout: [acc 1024][w1f 24576][b1 384][b2 320][b3 256][w2f 15360][w3f 12288]
    float*          acc = (float*)ws;
    unsigned short* w1f = (unsigned short*)(ws + 1024);
    float*          b1p = (float*)(ws + 25600);
    float*          b2p = (float*)(ws + 25984);
    float*          b3p = (float*)(ws + 26304);
    unsigned short* w2f = (unsigned short*)(ws + 26560);
    unsigned short* w3f = (unsigned short*)(ws + 41920);

    hipMemsetAsync(acc, 0, 1024, stream);
    repack<<<52, 64, 0, stream>>>(W1, b1, W2, b2, W3, b3, w1f, w2f, w3f, b1p, b2p, b3p);
    // 1024 blocks x 4 waves x 4 passes x 16 rows = 262144 rows
    mlp_main<<<NROWS / (4 * PASSES * 16), 256, 0, stream>>>(
        x, (const f32x4*)(ws + 1024), w2f, w3f, acc);
    finalize_k<<<1, 64, 0, stream>>>(acc, (float*)d_out);
}